// Round 5
// baseline (453.072 us; speedup 1.0000x reference)
//
#include <hip/hip_runtime.h>
#include <cstdint>
#include <cstddef>

#define L_LAYERS 3
#define H_HEADS 8
#define D_EMB 128
#define DKV 16
#define FF_DIM 512
#define B_BATCH 32
#define N_SEQ 512
#define F_INP 16
#define OUT_DIM 3
#define M_ROWS (B_BATCH * N_SEQ)   // 16384

typedef unsigned short ushort_t;
typedef unsigned int uint_t;
typedef __attribute__((ext_vector_type(8))) short short8;
typedef __attribute__((ext_vector_type(4))) float f32x4;
typedef __attribute__((ext_vector_type(16))) float f32x16;

__device__ inline ushort_t f2bf(float x) {   // RNE float->bf16
    union { float f; uint_t u; } v; v.f = x;
    uint_t r = v.u + 0x7fffu + ((v.u >> 16) & 1u);
    return (ushort_t)(r >> 16);
}

__device__ inline uint_t pack2bf(float a, float b) {  // RNE pack: lo=a, hi=b
    union { float f; uint_t u; } ua, ub;
    ua.f = a; ub.f = b;
    uint_t ra = ua.u + 0x7fffu + ((ua.u >> 16) & 1u);
    uint_t rb = ub.u + 0x7fffu + ((ub.u >> 16) & 1u);
    return (ra >> 16) | (rb & 0xffff0000u);
}

__device__ inline void gload16(const void* g, void* l) {
    __builtin_amdgcn_global_load_lds(
        (const __attribute__((address_space(1))) unsigned int*)g,
        (__attribute__((address_space(3))) unsigned int*)l, 16, 0, 0);
}

// ---------------- mask bit-pack ----------------
__global__ __launch_bounds__(256) void pack_mask_kernel(const int* __restrict__ mask,
                                                        unsigned long long* __restrict__ pm) {
    int gid = blockIdx.x * 256 + threadIdx.x;
    int v = mask[gid];
    unsigned long long bal = __ballot(v != 0);
    if ((threadIdx.x & 63) == 0) pm[gid >> 6] = bal;
}

// -------- Wq/Wk/Wv [L,H,D,DK] -> bf16 B^T layout [L][n=proj*128+h*16+k][d] --------
__global__ __launch_bounds__(256) void repack_qkv_bt_kernel(const float* __restrict__ Wq,
                                                            const float* __restrict__ Wk,
                                                            const float* __restrict__ Wv,
                                                            ushort_t* __restrict__ dst) {
    int idx = blockIdx.x * 256 + threadIdx.x;   // exactly L*384*128
    int d = idx & 127;
    int n = (idx >> 7) % 384;
    int l = idx / (384 * 128);
    int proj = n >> 7, hh = (n & 127) >> 4, kk = n & 15;
    const float* src = proj == 0 ? Wq : proj == 1 ? Wk : Wv;
    dst[idx] = f2bf(src[((size_t)(l * 8 + hh) * 128 + d) * 16 + kk]);
}

// -------- generic batched transpose to bf16: dst[b][c][r] = src[b][r][c] --------
__global__ __launch_bounds__(256) void tr_bf16_kernel(const float* __restrict__ src,
                                                      ushort_t* __restrict__ dst,
                                                      int R, int C, int total) {
    int idx = blockIdx.x * 256 + threadIdx.x;
    if (idx >= total) return;
    int b = idx / (R * C);
    int rem = idx - b * (R * C);
    int r = rem / C, c = rem - r * C;
    dst[(size_t)b * R * C + (size_t)c * R + r] = f2bf(src[idx]);
}

// ---------------- embed: h = relu(x @ We), write fp32 + bf16 ----------------
__global__ __launch_bounds__(256) void embed_kernel(const float* __restrict__ x,
                                                    const float* __restrict__ We,
                                                    float* __restrict__ hf,
                                                    ushort_t* __restrict__ hb) {
    const int t = threadIdx.x;
    const int d = t & 127;
    const int m = blockIdx.x * 2 + (t >> 7);
    const float* xr = x + (size_t)m * 16;
    float acc = 0.f;
#pragma unroll
    for (int k = 0; k < 16; k++) acc += xr[k] * We[k * 128 + d];
    acc = fmaxf(acc, 0.f);
    hf[(size_t)m * 128 + d] = acc;
    hb[(size_t)m * 128 + d] = f2bf(acc);
}

// ---------------- bf16 MFMA GEMM: C = [relu]([qsc]*(A @ Bt^T) [+bias] [+Cin]) ----------------
template <int BM, int BN, bool QS, bool RELU, bool BIAS, bool RES, bool WF32, bool WB16>
__global__ __launch_bounds__(256) void gemm_bt(const ushort_t* __restrict__ A,
                                               const ushort_t* __restrict__ Bt,
                                               const float* __restrict__ bias,
                                               const float* __restrict__ Cin,
                                               float* __restrict__ Cf,
                                               ushort_t* __restrict__ Cb,
                                               int M, int N, int K) {
    constexpr int NI = (BM == 128) ? 4 : ((BN == 128) ? 4 : 2);
    constexpr int NJ = (BN == 128) ? ((BM == 128) ? 4 : 2) : 2;
    __shared__ __align__(16) ushort_t Asm[BM * 32];
    __shared__ __align__(16) ushort_t Bsm[BN * 32];
    const int tid = threadIdx.x;
    const int w = tid >> 6, l = tid & 63;
    const int m0 = blockIdx.y * BM, n0 = blockIdx.x * BN;
    const int WM = (BM == 128) ? (w & 1) * 64 : ((BN == 64) ? (w & 1) * 32 : 0);
    const int WN = (BM == 128) ? (w >> 1) * 64 : ((BN == 64) ? (w >> 1) * 32 : w * 32);
    const int lr = l & 15, lq = l >> 4;
    const int sar = w * 16 + (l >> 2);
    const int sac = (l & 3) * 8;

    f32x4 acc[NI][NJ];
#pragma unroll
    for (int i = 0; i < NI; i++)
#pragma unroll
        for (int j = 0; j < NJ; j++) acc[i][j] = (f32x4){0.f, 0.f, 0.f, 0.f};

    for (int k0 = 0; k0 < K; k0 += 32) {
#pragma unroll
        for (int it = 0; it < BM / 64; it++)
            gload16(A + (size_t)(m0 + it * 64 + sar) * K + k0 + sac,
                    &Asm[(it * 64 + sar) * 32 + sac]);
#pragma unroll
        for (int it = 0; it < BN / 64; it++)
            gload16(Bt + (size_t)(n0 + it * 64 + sar) * K + k0 + sac,
                    &Bsm[(it * 64 + sar) * 32 + sac]);
        __syncthreads();
        short8 af[NI], bfr[NJ];
#pragma unroll
        for (int i = 0; i < NI; i++)
            af[i] = *(const short8*)&Asm[(WM + i * 16 + lr) * 32 + lq * 8];
#pragma unroll
        for (int j = 0; j < NJ; j++)
            bfr[j] = *(const short8*)&Bsm[(WN + j * 16 + lr) * 32 + lq * 8];
#pragma unroll
        for (int i = 0; i < NI; i++)
#pragma unroll
            for (int j = 0; j < NJ; j++)
                acc[i][j] = __builtin_amdgcn_mfma_f32_16x16x32_bf16(af[i], bfr[j], acc[i][j], 0, 0, 0);
        __syncthreads();
    }

    const float qsc = (QS && blockIdx.x == 0) ? 0.25f : 1.0f;
    float bv[NJ];
#pragma unroll
    for (int j = 0; j < NJ; j++) {
        const int n = n0 + WN + j * 16 + lr;
        bv[j] = BIAS ? bias[n] : 0.f;
    }
#pragma unroll
    for (int i = 0; i < NI; i++) {
#pragma unroll
        for (int r = 0; r < 4; r++) {
            const int m = m0 + WM + i * 16 + lq * 4 + r;
#pragma unroll
            for (int j = 0; j < NJ; j++) {
                const int n = n0 + WN + j * 16 + lr;
                float v = acc[i][j][r] * qsc + bv[j];
                if (RES) v += Cin[(size_t)m * N + n];
                if (RELU) v = fmaxf(v, 0.f);
                if (WF32) Cf[(size_t)m * N + n] = v;
                if (WB16) Cb[(size_t)m * N + n] = f2bf(v);
            }
        }
    }
}

// ---------------- MFMA flash attention v3: S^T via 32x32x16, two-pass softmax ----------------
// qkv bf16 [16384][384]: q(prescaled x0.25)=h*16+k, k=128+h*16+k, v=256+h*16+k.
// Block = (b,h,half): 512 blocks x 512 thr (8 waves). Wave owns 32 queries.
// S^T = K·Q^T via mfma_32x32x16 (K=16 exact, no zero-pad). C-layout [key][q]:
// lane holds col q=lane&31, rows(keys)=(r&3)+8*(r>>2)+4*(lane>>5) -> per-q stats in-lane.
// Pass1: raw-score max (mask-indep, shift-invariant). Pass2: recompute S, exp, mask-zero,
// pack P pairs -> LDS (b64), PV via mfma_16x16x32 from LDS. Normalize once at end.
__global__ __launch_bounds__(512, 4) void attn_mfma_kernel(const ushort_t* __restrict__ qkv,
                                                           const uint_t* __restrict__ pm,
                                                           ushort_t* __restrict__ Aout) {
    __shared__ __align__(16) ushort_t KF[16 * 512];   // K in 32x32x16 A-frag layout, 16 tiles
    __shared__ __align__(16) ushort_t Vt[16 * 520];   // V^T [dv][key]
    __shared__ __align__(16) ushort_t Ps[8][32 * 72]; // per-wave P [32 q][64 key], stride 72

    const int tid = threadIdx.x;
    const int w = tid >> 6, L = tid & 63;
    const int lane31 = L & 31, lhalf = L >> 5;
    const int lr = L & 15, lq = L >> 4;
    const int bx = blockIdx.x;
    const int b = bx >> 4, h = (bx >> 1) & 7, half_blk = bx & 1;
    const size_t base = (size_t)b * 512 * 384;

    // K staging directly in A-frag layout: tile t, lane L holds K[t*32+(L&31)][ (L>>5)*8 + j ]
#pragma unroll
    for (int i = 0; i < 2; i++) {
        const int t = w + i * 8;
        const ushort_t* src = qkv + base + (size_t)(t * 32 + lane31) * 384 + 128 + h * 16 + lhalf * 8;
        gload16(src, &KF[t * 512 + L * 8]);
    }
    // V transpose staging (one-time)
    {
        const ushort_t* gv = qkv + base + (size_t)tid * 384 + 256 + h * 16;
        ushort_t tmp[16];
        *(uint4*)tmp = *(const uint4*)gv;
        *(uint4*)(tmp + 8) = *(const uint4*)(gv + 8);
#pragma unroll
        for (int d = 0; d < 16; d++) Vt[d * 520 + tid] = tmp[d];
    }
    __syncthreads();

    const int q0 = (half_blk * 8 + w) * 32;
    // Q B-frag (persistent): B[n=q][k=dk], lane L: q=q0+(L&31), dk=(L>>5)*8+j
    const short8 qf = *(const short8*)(qkv + base + (size_t)(q0 + lane31) * 384 + h * 16 + lhalf * 8);
    // mask words for this lane's q: 16 words (one per 32-key tile)
    const uint_t* pmr = pm + (size_t)(b * 512 + q0 + lane31) * 16;
    const uint4 mwa = *(const uint4*)(pmr);
    const uint4 mwb = *(const uint4*)(pmr + 4);
    const uint4 mwc = *(const uint4*)(pmr + 8);
    const uint4 mwd = *(const uint4*)(pmr + 12);
    const uint_t mw[16] = {mwa.x, mwa.y, mwa.z, mwa.w, mwb.x, mwb.y, mwb.z, mwb.w,
                           mwc.x, mwc.y, mwc.z, mwc.w, mwd.x, mwd.y, mwd.z, mwd.w};

    const f32x16 zero16 = (f32x16)(0.f);

    // ---- pass 1: per-q raw max (in-lane over regs, then one cross-half shuffle) ----
    float mx = -1e30f;
#pragma unroll
    for (int t = 0; t < 16; t++) {
        short8 kf = *(const short8*)&KF[t * 512 + L * 8];
        f32x16 s = __builtin_amdgcn_mfma_f32_32x32x16_bf16(kf, qf, zero16, 0, 0, 0);
#pragma unroll
        for (int r = 0; r < 16; r++) mx = fmaxf(mx, s[r]);
    }
    mx = fmaxf(mx, __shfl_xor(mx, 32));

    // ---- pass 2: exp + mask + PV over 8 chunks of 64 keys ----
    float lsum = 0.f;
    f32x4 oacc0 = (f32x4){0.f, 0.f, 0.f, 0.f};
    f32x4 oacc1 = (f32x4){0.f, 0.f, 0.f, 0.f};
#pragma unroll
    for (int c = 0; c < 8; c++) {
        float p[32];
#pragma unroll
        for (int tt = 0; tt < 2; tt++) {
            const int t = c * 2 + tt;
            short8 kf = *(const short8*)&KF[t * 512 + L * 8];
            f32x16 s = __builtin_amdgcn_mfma_f32_32x32x16_bf16(kf, qf, zero16, 0, 0, 0);
            const uint_t word = mw[t];
#pragma unroll
            for (int r = 0; r < 16; r++) {
                const int keyl = (r & 3) + 8 * (r >> 2) + 4 * lhalf;
                const float e = __expf(s[r] - mx);
                const float pv = (word & (1u << keyl)) ? e : 0.f;
                p[tt * 16 + r] = pv;
                lsum += pv;
            }
        }
        // pack groups of 4 consecutive keys (regs 4g..4g+3 = keys g*8+4*half .. +3)
#pragma unroll
        for (int tt = 0; tt < 2; tt++) {
#pragma unroll
            for (int g = 0; g < 4; g++) {
                const uint_t lo = pack2bf(p[tt * 16 + g * 4 + 0], p[tt * 16 + g * 4 + 1]);
                const uint_t hi = pack2bf(p[tt * 16 + g * 4 + 2], p[tt * 16 + g * 4 + 3]);
                const int key = tt * 32 + g * 8 + 4 * lhalf;   // chunk-local
                *(uint2*)&Ps[w][lane31 * 72 + key] = make_uint2(lo, hi);
            }
        }
        // PV: O[q][dv] tiles, A=P from LDS, B=V^T from LDS (no barrier: per-wave LDS)
#pragma unroll
        for (int ks = 0; ks < 2; ks++) {
            short8 vb = *(const short8*)&Vt[lr * 520 + c * 64 + ks * 32 + lq * 8];
            short8 pa0 = *(const short8*)&Ps[w][lr * 72 + ks * 32 + lq * 8];
            short8 pa1 = *(const short8*)&Ps[w][(16 + lr) * 72 + ks * 32 + lq * 8];
            oacc0 = __builtin_amdgcn_mfma_f32_16x16x32_bf16(pa0, vb, oacc0, 0, 0, 0);
            oacc1 = __builtin_amdgcn_mfma_f32_16x16x32_bf16(pa1, vb, oacc1, 0, 0, 0);
        }
    }
    lsum += __shfl_xor(lsum, 32);

    // ---- normalize + write: C 16x16 layout: col=dv=lr, row=lq*4+rr ----
#pragma unroll
    for (int qa = 0; qa < 2; qa++) {
        const f32x4 oa = qa ? oacc1 : oacc0;
#pragma unroll
        for (int rr = 0; rr < 4; rr++) {
            const int qloc = qa * 16 + lq * 4 + rr;
            const float ls = __shfl(lsum, qloc, 64);
            const float ov = oa[rr] / ls;
            Aout[(size_t)(b * 512 + q0 + qloc) * 128 + h * 16 + lr] = f2bf(ov);
        }
    }
}

// ------------- pooled readout part (512 thr) -------------
__global__ __launch_bounds__(512) void pool_kernel(const float* __restrict__ h,
                                                   const float* __restrict__ Wp,
                                                   const float* __restrict__ Wr,
                                                   const float* __restrict__ br,
                                                   float* __restrict__ pb) {
    const int b = blockIdx.x, t = threadIdx.x;
    const int d = t & 127, g = t >> 7;
    __shared__ float part[4][128];
    __shared__ float pooled[128];
    __shared__ float rp[128];
    float acc = 0.f;
    const float* hb = h + (size_t)b * N_SEQ * D_EMB;
    for (int n = g; n < N_SEQ; n += 4) acc += hb[n * D_EMB + d];
    part[g][d] = acc;
    __syncthreads();
    if (t < 128) pooled[t] = (part[0][t] + part[1][t] + part[2][t] + part[3][t]) * (1.0f / N_SEQ);
    __syncthreads();
    float a2 = 0.f;
    for (int dd = g * 32; dd < g * 32 + 32; dd++) a2 += pooled[dd] * Wp[dd * 128 + d];
    part[g][d] = a2;
    __syncthreads();
    if (t < 128) rp[t] = fmaxf(part[0][t] + part[1][t] + part[2][t] + part[3][t], 0.f);
    __syncthreads();
    if (t < OUT_DIM) {
        float a = br[t];
        for (int j = 0; j < D_EMB; j++) a += rp[j] * Wr[j * OUT_DIM + t];
        pb[b * OUT_DIM + t] = a;
    }
}

// ------------- final readout -------------
__global__ __launch_bounds__(128) void out_kernel(const float* __restrict__ h,
                                                  const float* __restrict__ Wr,
                                                  const float* __restrict__ pb,
                                                  float* __restrict__ out) {
    const int row = blockIdx.x, tid = threadIdx.x;
    __shared__ float rp[128];
    rp[tid] = fmaxf(h[(size_t)row * D_EMB + tid], 0.f);
    __syncthreads();
    if (tid < 96) {
        const int o = tid >> 5, j0 = tid & 31;
        float acc = 0.f;
        for (int j = j0; j < 128; j += 32) acc += rp[j] * Wr[(128 + j) * OUT_DIM + o];
        for (int off = 16; off; off >>= 1) acc += __shfl_down(acc, off, 32);
        if (j0 == 0) out[(size_t)row * OUT_DIM + o] = acc + pb[(row >> 9) * OUT_DIM + o];
    }
}

extern "C" void kernel_launch(void* const* d_in, const int* in_sizes, int n_in,
                              void* d_out, int out_size, void* d_ws, size_t ws_size,
                              hipStream_t stream) {
    const float* x    = (const float*)d_in[0];
    const int*   mask = (const int*)d_in[1];
    const float* We   = (const float*)d_in[2];
    const float* Wq   = (const float*)d_in[3];
    const float* Wk   = (const float*)d_in[4];
    const float* Wv   = (const float*)d_in[5];
    const float* Wout = (const float*)d_in[6];
    const float* Wff1 = (const float*)d_in[7];
    const float* bff1 = (const float*)d_in[8];
    const float* Wff2 = (const float*)d_in[9];
    const float* bff2 = (const float*)d_in[10];
    const float* Wp   = (const float*)d_in[11];
    const float* Wr   = (const float*)d_in[12];
    const float* br   = (const float*)d_in[13];
    float* out = (float*)d_out;

    char* ws = (char*)d_ws;
    unsigned long long* pm64 = (unsigned long long*)(ws + 0);        // 1 MiB
    const uint_t* pm32       = (const uint_t*)(ws + 0);
    ushort_t* wqkvT = (ushort_t*)(ws + 1048576);                     // 288 KiB
    ushort_t* woutT = (ushort_t*)(ws + 1343488);                     // 96 KiB
    ushort_t* wff1T = (ushort_t*)(ws + 1441792);                     // 384 KiB
    ushort_t* wff2T = (ushort_t*)(ws + 1835008);                     // 384 KiB
    float*    pbbuf = (float*)(ws + 2228224);                        // 384 B
    float*    hbuf  = (float*)(ws + 4194304);                        // 8 MiB fp32 residual
    ushort_t* hb16  = (ushort_t*)(ws + 12582912);                    // 4 MiB bf16 mirror of h
    ushort_t* qkv16 = (ushort_t*)(ws + 16777216);                    // 12 MiB bf16 QKV
    ushort_t* t16   = (ushort_t*)(ws + 16777216);                    // 16 MiB bf16 FFN mid (aliases qkv16)
    ushort_t* a16   = (ushort_t*)(ws + 41943040);                    // 4 MiB bf16 attn out

    pack_mask_kernel<<<(B_BATCH * N_SEQ * N_SEQ) / 256, 256, 0, stream>>>(mask, pm64);
    repack_qkv_bt_kernel<<<576, 256, 0, stream>>>(Wq, Wk, Wv, wqkvT);
    tr_bf16_kernel<<<192, 256, 0, stream>>>(Wout, woutT, 128, 128, 3 * 128 * 128);
    tr_bf16_kernel<<<768, 256, 0, stream>>>(Wff1, wff1T, 128, 512, 3 * 128 * 512);
    tr_bf16_kernel<<<768, 256, 0, stream>>>(Wff2, wff2T, 512, 128, 3 * 512 * 128);

    embed_kernel<<<M_ROWS / 2, 256, 0, stream>>>(x, We, hbuf, hb16);

    for (int l = 0; l < L_LAYERS; l++) {
        // QKV (Q prescaled by 0.25 in epilogue of block x=0)
        gemm_bt<128, 128, true, false, false, false, false, true>
            <<<dim3(3, M_ROWS / 128), 256, 0, stream>>>(
            hb16, wqkvT + (size_t)l * 384 * 128, nullptr, nullptr, nullptr, qkv16,
            M_ROWS, 384, 128);
        // MFMA flash attention v3 -> a16 bf16
        attn_mfma_kernel<<<512, 512, 0, stream>>>(qkv16, pm32, a16);
        // h += a16 @ Wout   (64x64 tiles)
        gemm_bt<64, 64, false, false, false, true, true, true>
            <<<dim3(2, M_ROWS / 64), 256, 0, stream>>>(
            a16, woutT + (size_t)l * 128 * 128, nullptr, hbuf, hbuf, hb16,
            M_ROWS, 128, 128);
        // t = relu(h @ Wff1 + bff1)
        gemm_bt<128, 128, false, true, true, false, false, true>
            <<<dim3(4, M_ROWS / 128), 256, 0, stream>>>(
            hb16, wff1T + (size_t)l * 512 * 128, bff1 + l * 512, nullptr, nullptr, t16,
            M_ROWS, 512, 128);
        // h += t16 @ Wff2 + bff2   (64x64 tiles)
        gemm_bt<64, 64, false, false, true, true, true, true>
            <<<dim3(2, M_ROWS / 64), 256, 0, stream>>>(
            t16, wff2T + (size_t)l * 128 * 512, bff2 + l * 128, hbuf, hbuf, hb16,
            M_ROWS, 128, 512);
    }

    pool_kernel<<<B_BATCH, 512, 0, stream>>>(hbuf, Wp, Wr, br, pbbuf);
    out_kernel<<<M_ROWS, 128, 0, stream>>>(hbuf, Wr, pbbuf, out);
}

// Round 6
// 382.970 us; speedup vs baseline: 1.1831x; 1.1831x over previous
//
#include <hip/hip_runtime.h>
#include <cstdint>
#include <cstddef>

#define L_LAYERS 3
#define H_HEADS 8
#define D_EMB 128
#define DKV 16
#define FF_DIM 512
#define B_BATCH 32
#define N_SEQ 512
#define F_INP 16
#define OUT_DIM 3
#define M_ROWS (B_BATCH * N_SEQ)   // 16384

typedef unsigned short ushort_t;
typedef unsigned int uint_t;
typedef __attribute__((ext_vector_type(8))) short short8;
typedef __attribute__((ext_vector_type(4))) float f32x4;
typedef __attribute__((ext_vector_type(16))) float f32x16;

__device__ inline ushort_t f2bf(float x) {   // RNE float->bf16
    union { float f; uint_t u; } v; v.f = x;
    uint_t r = v.u + 0x7fffu + ((v.u >> 16) & 1u);
    return (ushort_t)(r >> 16);
}

__device__ inline uint_t pack2bf(float a, float b) {  // RNE pack: lo=a, hi=b
    union { float f; uint_t u; } ua, ub;
    ua.f = a; ub.f = b;
    uint_t ra = ua.u + 0x7fffu + ((ua.u >> 16) & 1u);
    uint_t rb = ub.u + 0x7fffu + ((ub.u >> 16) & 1u);
    return (ra >> 16) | (rb & 0xffff0000u);
}

__device__ inline void gload16(const void* g, void* l) {
    __builtin_amdgcn_global_load_lds(
        (const __attribute__((address_space(1))) unsigned int*)g,
        (__attribute__((address_space(3))) unsigned int*)l, 16, 0, 0);
}

// ---------------- fused preprocessing: pack_mask | repack_qkv | 3x transpose | embed ----------------
// All segments are mutually independent; one dispatch saves ~5 launch gaps.
#define PM_BLK 32768   // (B*N*N)/256
#define RQ_BLK 576     // L*384*128/256
#define TW_BLK 192     // 3*128*128/256
#define T1_BLK 768     // 3*128*512/256
#define T2_BLK 768
#define EM_BLK 8192    // M_ROWS/2
__global__ __launch_bounds__(256) void preproc_kernel(
        const int* __restrict__ mask, unsigned long long* __restrict__ pm,
        const float* __restrict__ Wq, const float* __restrict__ Wk,
        const float* __restrict__ Wv, ushort_t* __restrict__ wqkvT,
        const float* __restrict__ Wout, ushort_t* __restrict__ woutT,
        const float* __restrict__ Wff1, ushort_t* __restrict__ wff1T,
        const float* __restrict__ Wff2, ushort_t* __restrict__ wff2T,
        const float* __restrict__ x, const float* __restrict__ We,
        float* __restrict__ hf, ushort_t* __restrict__ hb) {
    int bx = blockIdx.x;
    const int tid = threadIdx.x;
    if (bx < PM_BLK) {                       // ---- mask bit-pack ----
        int gid = bx * 256 + tid;
        int v = mask[gid];
        unsigned long long bal = __ballot(v != 0);
        if ((tid & 63) == 0) pm[gid >> 6] = bal;
        return;
    }
    bx -= PM_BLK;
    if (bx < RQ_BLK) {                       // ---- Wq/Wk/Wv -> B^T bf16 ----
        int idx = bx * 256 + tid;
        int d = idx & 127;
        int n = (idx >> 7) % 384;
        int l = idx / (384 * 128);
        int proj = n >> 7, hh = (n & 127) >> 4, kk = n & 15;
        const float* src = proj == 0 ? Wq : proj == 1 ? Wk : Wv;
        wqkvT[idx] = f2bf(src[((size_t)(l * 8 + hh) * 128 + d) * 16 + kk]);
        return;
    }
    bx -= RQ_BLK;
    if (bx < TW_BLK + T1_BLK + T2_BLK) {     // ---- batched transposes ----
        const float* src; ushort_t* dst; int R, C;
        if (bx < TW_BLK) { src = Wout; dst = woutT; R = 128; C = 128; }
        else if (bx < TW_BLK + T1_BLK) { src = Wff1; dst = wff1T; R = 128; C = 512; bx -= TW_BLK; }
        else { src = Wff2; dst = wff2T; R = 512; C = 128; bx -= TW_BLK + T1_BLK; }
        int idx = bx * 256 + tid;
        int b = idx / (R * C);
        int rem = idx - b * (R * C);
        int r = rem / C, c = rem - r * C;
        dst[(size_t)b * R * C + (size_t)c * R + r] = f2bf(src[idx]);
        return;
    }
    bx -= TW_BLK + T1_BLK + T2_BLK;
    {                                        // ---- embed: h = relu(x @ We) ----
        const int d = tid & 127;
        const int m = bx * 2 + (tid >> 7);
        const float* xr = x + (size_t)m * 16;
        float acc = 0.f;
#pragma unroll
        for (int k = 0; k < 16; k++) acc += xr[k] * We[k * 128 + d];
        acc = fmaxf(acc, 0.f);
        hf[(size_t)m * 128 + d] = acc;
        hb[(size_t)m * 128 + d] = f2bf(acc);
    }
}

// ---------------- bf16 MFMA GEMM: C = [relu]([qsc]*(A @ Bt^T) [+bias] [+Cin]) ----------------
template <int BM, int BN, bool QS, bool RELU, bool BIAS, bool RES, bool WF32, bool WB16>
__global__ __launch_bounds__(256) void gemm_bt(const ushort_t* __restrict__ A,
                                               const ushort_t* __restrict__ Bt,
                                               const float* __restrict__ bias,
                                               const float* __restrict__ Cin,
                                               float* __restrict__ Cf,
                                               ushort_t* __restrict__ Cb,
                                               int M, int N, int K) {
    constexpr int NI = (BM == 128) ? 4 : ((BN == 128) ? 4 : 2);
    constexpr int NJ = (BN == 128) ? ((BM == 128) ? 4 : 2) : 2;
    __shared__ __align__(16) ushort_t Asm[BM * 32];
    __shared__ __align__(16) ushort_t Bsm[BN * 32];
    const int tid = threadIdx.x;
    const int w = tid >> 6, l = tid & 63;
    const int m0 = blockIdx.y * BM, n0 = blockIdx.x * BN;
    const int WM = (BM == 128) ? (w & 1) * 64 : ((BN == 64) ? (w & 1) * 32 : 0);
    const int WN = (BM == 128) ? (w >> 1) * 64 : ((BN == 64) ? (w >> 1) * 32 : w * 32);
    const int lr = l & 15, lq = l >> 4;
    const int sar = w * 16 + (l >> 2);
    const int sac = (l & 3) * 8;

    f32x4 acc[NI][NJ];
#pragma unroll
    for (int i = 0; i < NI; i++)
#pragma unroll
        for (int j = 0; j < NJ; j++) acc[i][j] = (f32x4){0.f, 0.f, 0.f, 0.f};

    for (int k0 = 0; k0 < K; k0 += 32) {
#pragma unroll
        for (int it = 0; it < BM / 64; it++)
            gload16(A + (size_t)(m0 + it * 64 + sar) * K + k0 + sac,
                    &Asm[(it * 64 + sar) * 32 + sac]);
#pragma unroll
        for (int it = 0; it < BN / 64; it++)
            gload16(Bt + (size_t)(n0 + it * 64 + sar) * K + k0 + sac,
                    &Bsm[(it * 64 + sar) * 32 + sac]);
        __syncthreads();
        short8 af[NI], bfr[NJ];
#pragma unroll
        for (int i = 0; i < NI; i++)
            af[i] = *(const short8*)&Asm[(WM + i * 16 + lr) * 32 + lq * 8];
#pragma unroll
        for (int j = 0; j < NJ; j++)
            bfr[j] = *(const short8*)&Bsm[(WN + j * 16 + lr) * 32 + lq * 8];
#pragma unroll
        for (int i = 0; i < NI; i++)
#pragma unroll
            for (int j = 0; j < NJ; j++)
                acc[i][j] = __builtin_amdgcn_mfma_f32_16x16x32_bf16(af[i], bfr[j], acc[i][j], 0, 0, 0);
        __syncthreads();
    }

    const float qsc = (QS && blockIdx.x == 0) ? 0.25f : 1.0f;
    float bv[NJ];
#pragma unroll
    for (int j = 0; j < NJ; j++) {
        const int n = n0 + WN + j * 16 + lr;
        bv[j] = BIAS ? bias[n] : 0.f;
    }
#pragma unroll
    for (int i = 0; i < NI; i++) {
#pragma unroll
        for (int r = 0; r < 4; r++) {
            const int m = m0 + WM + i * 16 + lq * 4 + r;
#pragma unroll
            for (int j = 0; j < NJ; j++) {
                const int n = n0 + WN + j * 16 + lr;
                float v = acc[i][j][r] * qsc + bv[j];
                if (RES) v += Cin[(size_t)m * N + n];
                if (RELU) v = fmaxf(v, 0.f);
                if (WF32) Cf[(size_t)m * N + n] = v;
                if (WB16) Cb[(size_t)m * N + n] = f2bf(v);
            }
        }
    }
}

// ---------------- MFMA flash attention v4: tile-at-a-time pass 2 (no spill) ----------------
// qkv bf16 [16384][384]: q(prescaled x0.25)=h*16+k, k=128+h*16+k, v=256+h*16+k.
// Block=(b,h,half): 512 blocks x 512 thr (8 waves), wave owns 32 queries.
// S^T = K·Q^T via mfma_32x32x16 (K=16 exact). C-layout [key][q]: per-q stats in-lane.
// Pass1: raw max. Pass2 per 32-key tile: recompute S, exp, mask-zero, pack->Ps (per-wave,
// single tile), 2x PV mfma immediately. Live regs ~90; launch_bounds(512,2) -> no spill.
__global__ __launch_bounds__(512, 2) void attn_mfma_kernel(const ushort_t* __restrict__ qkv,
                                                           const uint_t* __restrict__ pm,
                                                           ushort_t* __restrict__ Aout) {
    __shared__ __align__(16) ushort_t KF[16 * 512];   // K in 32x32x16 A-frag layout, 16 tiles
    __shared__ __align__(16) ushort_t Vt[16 * 520];   // V^T [dv][key]
    __shared__ __align__(16) ushort_t Ps[8][32 * 36]; // per-wave P, ONE 32-key tile [32q][32+4]

    const int tid = threadIdx.x;
    const int w = tid >> 6, L = tid & 63;
    const int lane31 = L & 31, lhalf = L >> 5;
    const int lr = L & 15, lq = L >> 4;
    const int bx = blockIdx.x;
    const int b = bx >> 4, h = (bx >> 1) & 7, half_blk = bx & 1;
    const size_t base = (size_t)b * 512 * 384;

    // K staging directly in A-frag layout
#pragma unroll
    for (int i = 0; i < 2; i++) {
        const int t = w + i * 8;
        const ushort_t* src = qkv + base + (size_t)(t * 32 + lane31) * 384 + 128 + h * 16 + lhalf * 8;
        gload16(src, &KF[t * 512 + L * 8]);
    }
    // V transpose staging
    {
        const ushort_t* gv = qkv + base + (size_t)tid * 384 + 256 + h * 16;
        ushort_t tmp[16];
        *(uint4*)tmp = *(const uint4*)gv;
        *(uint4*)(tmp + 8) = *(const uint4*)(gv + 8);
#pragma unroll
        for (int d = 0; d < 16; d++) Vt[d * 520 + tid] = tmp[d];
    }
    __syncthreads();

    const int q0 = (half_blk * 8 + w) * 32;
    const short8 qf = *(const short8*)(qkv + base + (size_t)(q0 + lane31) * 384 + h * 16 + lhalf * 8);
    const uint_t* pmr = pm + (size_t)(b * 512 + q0 + lane31) * 16;
    const uint4 mwa = *(const uint4*)(pmr);
    const uint4 mwb = *(const uint4*)(pmr + 4);
    const uint4 mwc = *(const uint4*)(pmr + 8);
    const uint4 mwd = *(const uint4*)(pmr + 12);
    const uint_t mw[16] = {mwa.x, mwa.y, mwa.z, mwa.w, mwb.x, mwb.y, mwb.z, mwb.w,
                           mwc.x, mwc.y, mwc.z, mwc.w, mwd.x, mwd.y, mwd.z, mwd.w};

    const f32x16 zero16 = (f32x16)(0.f);

    // ---- pass 1: per-q raw max ----
    float mx = -1e30f;
#pragma unroll
    for (int t = 0; t < 16; t++) {
        short8 kf = *(const short8*)&KF[t * 512 + L * 8];
        f32x16 s = __builtin_amdgcn_mfma_f32_32x32x16_bf16(kf, qf, zero16, 0, 0, 0);
#pragma unroll
        for (int r = 0; r < 16; r++) mx = fmaxf(mx, s[r]);
    }
    mx = fmaxf(mx, __shfl_xor(mx, 32));

    // ---- pass 2: per 32-key tile: exp + mask + pack + PV ----
    float lsum = 0.f;
    f32x4 oacc0 = (f32x4){0.f, 0.f, 0.f, 0.f};
    f32x4 oacc1 = (f32x4){0.f, 0.f, 0.f, 0.f};
#pragma unroll
    for (int t = 0; t < 16; t++) {
        short8 kf = *(const short8*)&KF[t * 512 + L * 8];
        f32x16 s = __builtin_amdgcn_mfma_f32_32x32x16_bf16(kf, qf, zero16, 0, 0, 0);
        const uint_t word = mw[t];
#pragma unroll
        for (int r = 0; r < 16; r++) {
            const int keyl = (r & 3) + 8 * (r >> 2) + 4 * lhalf;
            const float e = __expf(s[r] - mx);
            const float pv = (word & (1u << keyl)) ? e : 0.f;
            s[r] = pv;
            lsum += pv;
        }
        // pack: regs 4g..4g+3 = keys g*8+4*lhalf+0..3 (consecutive)
#pragma unroll
        for (int g = 0; g < 4; g++) {
            const uint_t lo = pack2bf(s[g * 4 + 0], s[g * 4 + 1]);
            const uint_t hi = pack2bf(s[g * 4 + 2], s[g * 4 + 3]);
            *(uint2*)&Ps[w][lane31 * 36 + g * 8 + 4 * lhalf] = make_uint2(lo, hi);
        }
        // PV for this tile (per-wave LDS, no barrier; compiler orders via lgkmcnt)
        short8 vb = *(const short8*)&Vt[lr * 520 + t * 32 + lq * 8];
        short8 pa0 = *(const short8*)&Ps[w][lr * 36 + lq * 8];
        short8 pa1 = *(const short8*)&Ps[w][(16 + lr) * 36 + lq * 8];
        oacc0 = __builtin_amdgcn_mfma_f32_16x16x32_bf16(pa0, vb, oacc0, 0, 0, 0);
        oacc1 = __builtin_amdgcn_mfma_f32_16x16x32_bf16(pa1, vb, oacc1, 0, 0, 0);
    }
    lsum += __shfl_xor(lsum, 32);

    // ---- normalize + write ----
#pragma unroll
    for (int qa = 0; qa < 2; qa++) {
        const f32x4 oa = qa ? oacc1 : oacc0;
#pragma unroll
        for (int rr = 0; rr < 4; rr++) {
            const int qloc = qa * 16 + lq * 4 + rr;
            const float ls = __shfl(lsum, qloc, 64);
            const float ov = oa[rr] / ls;
            Aout[(size_t)(b * 512 + q0 + qloc) * 128 + h * 16 + lr] = f2bf(ov);
        }
    }
}

// ------------- pooled readout part (512 thr) -------------
__global__ __launch_bounds__(512) void pool_kernel(const float* __restrict__ h,
                                                   const float* __restrict__ Wp,
                                                   const float* __restrict__ Wr,
                                                   const float* __restrict__ br,
                                                   float* __restrict__ pb) {
    const int b = blockIdx.x, t = threadIdx.x;
    const int d = t & 127, g = t >> 7;
    __shared__ float part[4][128];
    __shared__ float pooled[128];
    __shared__ float rp[128];
    float acc = 0.f;
    const float* hb = h + (size_t)b * N_SEQ * D_EMB;
    for (int n = g; n < N_SEQ; n += 4) acc += hb[n * D_EMB + d];
    part[g][d] = acc;
    __syncthreads();
    if (t < 128) pooled[t] = (part[0][t] + part[1][t] + part[2][t] + part[3][t]) * (1.0f / N_SEQ);
    __syncthreads();
    float a2 = 0.f;
    for (int dd = g * 32; dd < g * 32 + 32; dd++) a2 += pooled[dd] * Wp[dd * 128 + d];
    part[g][d] = a2;
    __syncthreads();
    if (t < 128) rp[t] = fmaxf(part[0][t] + part[1][t] + part[2][t] + part[3][t], 0.f);
    __syncthreads();
    if (t < OUT_DIM) {
        float a = br[t];
        for (int j = 0; j < D_EMB; j++) a += rp[j] * Wr[j * OUT_DIM + t];
        pb[b * OUT_DIM + t] = a;
    }
}

// ------------- final readout -------------
__global__ __launch_bounds__(128) void out_kernel(const float* __restrict__ h,
                                                  const float* __restrict__ Wr,
                                                  const float* __restrict__ pb,
                                                  float* __restrict__ out) {
    const int row = blockIdx.x, tid = threadIdx.x;
    __shared__ float rp[128];
    rp[tid] = fmaxf(h[(size_t)row * D_EMB + tid], 0.f);
    __syncthreads();
    if (tid < 96) {
        const int o = tid >> 5, j0 = tid & 31;
        float acc = 0.f;
        for (int j = j0; j < 128; j += 32) acc += rp[j] * Wr[(128 + j) * OUT_DIM + o];
        for (int off = 16; off; off >>= 1) acc += __shfl_down(acc, off, 32);
        if (j0 == 0) out[(size_t)row * OUT_DIM + o] = acc + pb[(row >> 9) * OUT_DIM + o];
    }
}

extern "C" void kernel_launch(void* const* d_in, const int* in_sizes, int n_in,
                              void* d_out, int out_size, void* d_ws, size_t ws_size,
                              hipStream_t stream) {
    const float* x    = (const float*)d_in[0];
    const int*   mask = (const int*)d_in[1];
    const float* We   = (const float*)d_in[2];
    const float* Wq   = (const float*)d_in[3];
    const float* Wk   = (const float*)d_in[4];
    const float* Wv   = (const float*)d_in[5];
    const float* Wout = (const float*)d_in[6];
    const float* Wff1 = (const float*)d_in[7];
    const float* bff1 = (const float*)d_in[8];
    const float* Wff2 = (const float*)d_in[9];
    const float* bff2 = (const float*)d_in[10];
    const float* Wp   = (const float*)d_in[11];
    const float* Wr   = (const float*)d_in[12];
    const float* br   = (const float*)d_in[13];
    float* out = (float*)d_out;

    char* ws = (char*)d_ws;
    unsigned long long* pm64 = (unsigned long long*)(ws + 0);        // 1 MiB
    const uint_t* pm32       = (const uint_t*)(ws + 0);
    ushort_t* wqkvT = (ushort_t*)(ws + 1048576);                     // 288 KiB
    ushort_t* woutT = (ushort_t*)(ws + 1343488);                     // 96 KiB
    ushort_t* wff1T = (ushort_t*)(ws + 1441792);                     // 384 KiB
    ushort_t* wff2T = (ushort_t*)(ws + 1835008);                     // 384 KiB
    float*    pbbuf = (float*)(ws + 2228224);                        // 384 B
    float*    hbuf  = (float*)(ws + 4194304);                        // 8 MiB fp32 residual
    ushort_t* hb16  = (ushort_t*)(ws + 12582912);                    // 4 MiB bf16 mirror of h
    ushort_t* qkv16 = (ushort_t*)(ws + 16777216);                    // 12 MiB bf16 QKV
    ushort_t* t16   = (ushort_t*)(ws + 16777216);                    // 16 MiB bf16 FFN mid (aliases qkv16)
    ushort_t* a16   = (ushort_t*)(ws + 41943040);                    // 4 MiB bf16 attn out

    // fused preprocessing (mask pack, weight repacks, embed) — one dispatch
    preproc_kernel<<<PM_BLK + RQ_BLK + TW_BLK + T1_BLK + T2_BLK + EM_BLK, 256, 0, stream>>>(
        mask, pm64, Wq, Wk, Wv, wqkvT, Wout, woutT, Wff1, wff1T, Wff2, wff2T,
        x, We, hbuf, hb16);

    for (int l = 0; l < L_LAYERS; l++) {
        // QKV (Q prescaled by 0.25 in epilogue of block x=0)
        gemm_bt<128, 128, true, false, false, false, false, true>
            <<<dim3(3, M_ROWS / 128), 256, 0, stream>>>(
            hb16, wqkvT + (size_t)l * 384 * 128, nullptr, nullptr, nullptr, qkv16,
            M_ROWS, 384, 128);
        // MFMA flash attention v4 -> a16 bf16
        attn_mfma_kernel<<<512, 512, 0, stream>>>(qkv16, pm32, a16);
        // h += a16 @ Wout   (64x64 tiles)
        gemm_bt<64, 64, false, false, false, true, true, true>
            <<<dim3(2, M_ROWS / 64), 256, 0, stream>>>(
            a16, woutT + (size_t)l * 128 * 128, nullptr, hbuf, hbuf, hb16,
            M_ROWS, 128, 128);
        // t = relu(h @ Wff1 + bff1)
        gemm_bt<128, 128, false, true, true, false, false, true>
            <<<dim3(4, M_ROWS / 128), 256, 0, stream>>>(
            hb16, wff1T + (size_t)l * 512 * 128, bff1 + l * 512, nullptr, nullptr, t16,
            M_ROWS, 512, 128);
        // h += t16 @ Wff2 + bff2   (64x64 tiles)
        gemm_bt<64, 64, false, false, true, true, true, true>
            <<<dim3(2, M_ROWS / 64), 256, 0, stream>>>(
            t16, wff2T + (size_t)l * 128 * 512, bff2 + l * 128, hbuf, hbuf, hb16,
            M_ROWS, 128, 512);
    }

    pool_kernel<<<B_BATCH, 512, 0, stream>>>(hbuf, Wp, Wr, br, pbbuf);
    out_kernel<<<M_ROWS, 128, 0, stream>>>(hbuf, Wr, pbbuf, out);
}

// Round 7
// 341.536 us; speedup vs baseline: 1.3266x; 1.1213x over previous
//
#include <hip/hip_runtime.h>
#include <cstdint>
#include <cstddef>

#define L_LAYERS 3
#define H_HEADS 8
#define D_EMB 128
#define DKV 16
#define FF_DIM 512
#define B_BATCH 32
#define N_SEQ 512
#define F_INP 16
#define OUT_DIM 3
#define M_ROWS (B_BATCH * N_SEQ)   // 16384

typedef unsigned short ushort_t;
typedef unsigned int uint_t;
typedef __attribute__((ext_vector_type(8))) short short8;
typedef __attribute__((ext_vector_type(4))) float f32x4;
typedef __attribute__((ext_vector_type(16))) float f32x16;

__device__ inline ushort_t f2bf(float x) {   // RNE float->bf16
    union { float f; uint_t u; } v; v.f = x;
    uint_t r = v.u + 0x7fffu + ((v.u >> 16) & 1u);
    return (ushort_t)(r >> 16);
}

__device__ inline uint_t pack2bf(float a, float b) {  // RNE pack: lo=a, hi=b
    union { float f; uint_t u; } ua, ub;
    ua.f = a; ub.f = b;
    uint_t ra = ua.u + 0x7fffu + ((ua.u >> 16) & 1u);
    uint_t rb = ub.u + 0x7fffu + ((ub.u >> 16) & 1u);
    return (ra >> 16) | (rb & 0xffff0000u);
}

__device__ inline void gload16(const void* g, void* l) {
    __builtin_amdgcn_global_load_lds(
        (const __attribute__((address_space(1))) unsigned int*)g,
        (__attribute__((address_space(3))) unsigned int*)l, 16, 0, 0);
}

// ---------------- fused preprocessing: pack_mask | repack_qkv | 3x transpose | embed ----------------
#define PM_BLK 32768   // (B*N*N)/256
#define RQ_BLK 576     // L*384*128/256
#define TW_BLK 192     // 3*128*128/256
#define T1_BLK 768     // 3*128*512/256
#define T2_BLK 768
#define EM_BLK 8192    // M_ROWS/2
__global__ __launch_bounds__(256) void preproc_kernel(
        const int* __restrict__ mask, unsigned long long* __restrict__ pm,
        const float* __restrict__ Wq, const float* __restrict__ Wk,
        const float* __restrict__ Wv, ushort_t* __restrict__ wqkvT,
        const float* __restrict__ Wout, ushort_t* __restrict__ woutT,
        const float* __restrict__ Wff1, ushort_t* __restrict__ wff1T,
        const float* __restrict__ Wff2, ushort_t* __restrict__ wff2T,
        const float* __restrict__ x, const float* __restrict__ We,
        float* __restrict__ hf, ushort_t* __restrict__ hb) {
    int bx = blockIdx.x;
    const int tid = threadIdx.x;
    if (bx < PM_BLK) {                       // ---- mask bit-pack ----
        int gid = bx * 256 + tid;
        int v = mask[gid];
        unsigned long long bal = __ballot(v != 0);
        if ((tid & 63) == 0) pm[gid >> 6] = bal;
        return;
    }
    bx -= PM_BLK;
    if (bx < RQ_BLK) {                       // ---- Wq/Wk/Wv -> B^T bf16 ----
        int idx = bx * 256 + tid;
        int d = idx & 127;
        int n = (idx >> 7) % 384;
        int l = idx / (384 * 128);
        int proj = n >> 7, hh = (n & 127) >> 4, kk = n & 15;
        const float* src = proj == 0 ? Wq : proj == 1 ? Wk : Wv;
        wqkvT[idx] = f2bf(src[((size_t)(l * 8 + hh) * 128 + d) * 16 + kk]);
        return;
    }
    bx -= RQ_BLK;
    if (bx < TW_BLK + T1_BLK + T2_BLK) {     // ---- batched transposes ----
        const float* src; ushort_t* dst; int R, C;
        if (bx < TW_BLK) { src = Wout; dst = woutT; R = 128; C = 128; }
        else if (bx < TW_BLK + T1_BLK) { src = Wff1; dst = wff1T; R = 128; C = 512; bx -= TW_BLK; }
        else { src = Wff2; dst = wff2T; R = 512; C = 128; bx -= TW_BLK + T1_BLK; }
        int idx = bx * 256 + tid;
        int b = idx / (R * C);
        int rem = idx - b * (R * C);
        int r = rem / C, c = rem - r * C;
        dst[(size_t)b * R * C + (size_t)c * R + r] = f2bf(src[idx]);
        return;
    }
    bx -= TW_BLK + T1_BLK + T2_BLK;
    {                                        // ---- embed: h = relu(x @ We) ----
        const int d = tid & 127;
        const int m = bx * 2 + (tid >> 7);
        const float* xr = x + (size_t)m * 16;
        float acc = 0.f;
#pragma unroll
        for (int k = 0; k < 16; k++) acc += xr[k] * We[k * 128 + d];
        acc = fmaxf(acc, 0.f);
        hf[(size_t)m * 128 + d] = acc;
        hb[(size_t)m * 128 + d] = f2bf(acc);
    }
}

// ---------------- bf16 MFMA GEMM (QKV): C = qsc*(A @ Bt^T), bf16 out ----------------
__global__ __launch_bounds__(256) void gemm_qkv(const ushort_t* __restrict__ A,
                                                const ushort_t* __restrict__ Bt,
                                                ushort_t* __restrict__ Cb,
                                                int M, int N, int K) {
    __shared__ __align__(16) ushort_t Asm[128 * 32];
    __shared__ __align__(16) ushort_t Bsm[128 * 32];
    const int tid = threadIdx.x;
    const int w = tid >> 6, l = tid & 63;
    const int m0 = blockIdx.y * 128, n0 = blockIdx.x * 128;
    const int WM = (w & 1) * 64, WN = (w >> 1) * 64;
    const int lr = l & 15, lq = l >> 4;
    const int sar = w * 16 + (l >> 2);
    const int sac = (l & 3) * 8;

    f32x4 acc[4][4];
#pragma unroll
    for (int i = 0; i < 4; i++)
#pragma unroll
        for (int j = 0; j < 4; j++) acc[i][j] = (f32x4){0.f, 0.f, 0.f, 0.f};

    for (int k0 = 0; k0 < K; k0 += 32) {
#pragma unroll
        for (int it = 0; it < 2; it++)
            gload16(A + (size_t)(m0 + it * 64 + sar) * K + k0 + sac,
                    &Asm[(it * 64 + sar) * 32 + sac]);
#pragma unroll
        for (int it = 0; it < 2; it++)
            gload16(Bt + (size_t)(n0 + it * 64 + sar) * K + k0 + sac,
                    &Bsm[(it * 64 + sar) * 32 + sac]);
        __syncthreads();
        short8 af[4], bfr[4];
#pragma unroll
        for (int i = 0; i < 4; i++)
            af[i] = *(const short8*)&Asm[(WM + i * 16 + lr) * 32 + lq * 8];
#pragma unroll
        for (int j = 0; j < 4; j++)
            bfr[j] = *(const short8*)&Bsm[(WN + j * 16 + lr) * 32 + lq * 8];
#pragma unroll
        for (int i = 0; i < 4; i++)
#pragma unroll
            for (int j = 0; j < 4; j++)
                acc[i][j] = __builtin_amdgcn_mfma_f32_16x16x32_bf16(af[i], bfr[j], acc[i][j], 0, 0, 0);
        __syncthreads();
    }

    const float qsc = (blockIdx.x == 0) ? 0.25f : 1.0f;   // Q prescale
#pragma unroll
    for (int i = 0; i < 4; i++) {
#pragma unroll
        for (int r = 0; r < 4; r++) {
            const int m = m0 + WM + i * 16 + lq * 4 + r;
#pragma unroll
            for (int j = 0; j < 4; j++) {
                const int n = n0 + WN + j * 16 + lr;
                Cb[(size_t)m * N + n] = f2bf(acc[i][j][r] * qsc);
            }
        }
    }
}

// ---------------- fused layer tail: C1 = a16@Wout^T + h; T = relu(C1@W1^T+b1); h' = C1 + T@W2^T + b2 ----
// BM=32 rows/block, 512 blocks x 256 thr (4 waves). Wave w owns rows (2x16-tiles) x cols [w*32,+32)
// for phases A/C; cols [w*128,+128) for FF1. C1 kept fp32 in regs + bf16 in LDS; T lives in LDS only.
__global__ __launch_bounds__(256, 2) void tail_kernel(
        const ushort_t* __restrict__ A,     // a16 [16384][128]
        const ushort_t* __restrict__ WoT,   // [128 n][128 k]
        const ushort_t* __restrict__ W1T,   // [512 n][128 k]
        const ushort_t* __restrict__ W2T,   // [128 n][512 k]
        const float* __restrict__ b1,       // [512]
        const float* __restrict__ b2,       // [128]
        float* __restrict__ hf, ushort_t* __restrict__ hb) {
    // LDS carve (ushort units): As 32x32 @0 | Bs up-to 512x32 @1024 | C1b 32x136 @17408 | T 32x520 @21760
    __shared__ __align__(16) ushort_t sm[38400];          // 76.8 KB -> 2 blocks/CU
    ushort_t* As  = sm;
    ushort_t* Bs  = sm + 1024;
    ushort_t* C1b = sm + 17408;
    ushort_t* T   = sm + 21760;

    const int tid = threadIdx.x;
    const int w = tid >> 6, l = tid & 63;
    const int lr = l & 15, lq = l >> 4;
    const int srow = (l >> 2);              // staging row within 16-row group
    const int scol = (l & 3) * 8;           // staging col (ushort)
    const int m0 = blockIdx.x * 32;

    // ---------------- phase A: C1 = a16 @ WoT^T + h ----------------
    f32x4 c1a[2][2];
#pragma unroll
    for (int i = 0; i < 2; i++)
#pragma unroll
        for (int j = 0; j < 2; j++) c1a[i][j] = (f32x4){0.f, 0.f, 0.f, 0.f};

    for (int k0 = 0; k0 < 128; k0 += 32) {
        if (w < 2)
            gload16(A + (size_t)(m0 + w * 16 + srow) * 128 + k0 + scol,
                    &As[(w * 16 + srow) * 32 + scol]);
#pragma unroll
        for (int it = 0; it < 2; it++)
            gload16(WoT + (size_t)(it * 64 + w * 16 + srow) * 128 + k0 + scol,
                    &Bs[(it * 64 + w * 16 + srow) * 32 + scol]);
        __syncthreads();
        short8 af[2], bfr[2];
#pragma unroll
        for (int i = 0; i < 2; i++) af[i] = *(const short8*)&As[(i * 16 + lr) * 32 + lq * 8];
#pragma unroll
        for (int j = 0; j < 2; j++) bfr[j] = *(const short8*)&Bs[(w * 32 + j * 16 + lr) * 32 + lq * 8];
#pragma unroll
        for (int i = 0; i < 2; i++)
#pragma unroll
            for (int j = 0; j < 2; j++)
                c1a[i][j] = __builtin_amdgcn_mfma_f32_16x16x32_bf16(af[i], bfr[j], c1a[i][j], 0, 0, 0);
        __syncthreads();
    }
    // epilogue A: + residual h (fp32), keep fp32 in regs, write bf16 to C1b
    float c1[2][2][4];
#pragma unroll
    for (int i = 0; i < 2; i++)
#pragma unroll
        for (int r = 0; r < 4; r++) {
            const int row = i * 16 + lq * 4 + r;
#pragma unroll
            for (int j = 0; j < 2; j++) {
                const int n = w * 32 + j * 16 + lr;
                const float v = c1a[i][j][r] + hf[(size_t)(m0 + row) * 128 + n];
                c1[i][j][r] = v;
                C1b[row * 136 + n] = f2bf(v);
            }
        }
    __syncthreads();

    // ---------------- phase B: T = relu(C1 @ W1T^T + b1), wave w cols [w*128,+128) ----------------
    f32x4 ta[2][8];
#pragma unroll
    for (int i = 0; i < 2; i++)
#pragma unroll
        for (int j = 0; j < 8; j++) ta[i][j] = (f32x4){0.f, 0.f, 0.f, 0.f};

    for (int k0 = 0; k0 < 128; k0 += 32) {
#pragma unroll
        for (int it = 0; it < 8; it++)
            gload16(W1T + (size_t)(it * 64 + w * 16 + srow) * 128 + k0 + scol,
                    &Bs[(it * 64 + w * 16 + srow) * 32 + scol]);
        __syncthreads();
        short8 af[2], bfr[8];
#pragma unroll
        for (int i = 0; i < 2; i++) af[i] = *(const short8*)&C1b[(i * 16 + lr) * 136 + k0 + lq * 8];
#pragma unroll
        for (int j = 0; j < 8; j++) bfr[j] = *(const short8*)&Bs[(w * 128 + j * 16 + lr) * 32 + lq * 8];
#pragma unroll
        for (int i = 0; i < 2; i++)
#pragma unroll
            for (int j = 0; j < 8; j++)
                ta[i][j] = __builtin_amdgcn_mfma_f32_16x16x32_bf16(af[i], bfr[j], ta[i][j], 0, 0, 0);
        __syncthreads();
    }
    // epilogue B: +b1, relu, -> T bf16
#pragma unroll
    for (int j = 0; j < 8; j++) {
        const int n = w * 128 + j * 16 + lr;
        const float bv = b1[n];
#pragma unroll
        for (int i = 0; i < 2; i++)
#pragma unroll
            for (int r = 0; r < 4; r++) {
                const int row = i * 16 + lq * 4 + r;
                T[row * 520 + n] = f2bf(fmaxf(ta[i][j][r] + bv, 0.f));
            }
    }
    __syncthreads();

    // ---------------- phase C: h' = C1 + T @ W2T^T + b2 ----------------
    f32x4 oa[2][2];
#pragma unroll
    for (int i = 0; i < 2; i++)
#pragma unroll
        for (int j = 0; j < 2; j++) oa[i][j] = (f32x4){0.f, 0.f, 0.f, 0.f};

    for (int k0 = 0; k0 < 512; k0 += 32) {
#pragma unroll
        for (int it = 0; it < 2; it++)
            gload16(W2T + (size_t)(it * 64 + w * 16 + srow) * 512 + k0 + scol,
                    &Bs[(it * 64 + w * 16 + srow) * 32 + scol]);
        __syncthreads();
        short8 af[2], bfr[2];
#pragma unroll
        for (int i = 0; i < 2; i++) af[i] = *(const short8*)&T[(i * 16 + lr) * 520 + k0 + lq * 8];
#pragma unroll
        for (int j = 0; j < 2; j++) bfr[j] = *(const short8*)&Bs[(w * 32 + j * 16 + lr) * 32 + lq * 8];
#pragma unroll
        for (int i = 0; i < 2; i++)
#pragma unroll
            for (int j = 0; j < 2; j++)
                oa[i][j] = __builtin_amdgcn_mfma_f32_16x16x32_bf16(af[i], bfr[j], oa[i][j], 0, 0, 0);
        __syncthreads();
    }
    // epilogue C: + b2 + C1(fp32 regs) -> global fp32 + bf16
#pragma unroll
    for (int j = 0; j < 2; j++) {
        const int n = w * 32 + j * 16 + lr;
        const float bv = b2[n];
#pragma unroll
        for (int i = 0; i < 2; i++)
#pragma unroll
            for (int r = 0; r < 4; r++) {
                const int row = i * 16 + lq * 4 + r;
                const float v = oa[i][j][r] + bv + c1[i][j][r];
                hf[(size_t)(m0 + row) * 128 + n] = v;
                hb[(size_t)(m0 + row) * 128 + n] = f2bf(v);
            }
    }
}

// ---------------- MFMA flash attention v4 (unchanged from R6) ----------------
__global__ __launch_bounds__(512, 2) void attn_mfma_kernel(const ushort_t* __restrict__ qkv,
                                                           const uint_t* __restrict__ pm,
                                                           ushort_t* __restrict__ Aout) {
    __shared__ __align__(16) ushort_t KF[16 * 512];
    __shared__ __align__(16) ushort_t Vt[16 * 520];
    __shared__ __align__(16) ushort_t Ps[8][32 * 36];

    const int tid = threadIdx.x;
    const int w = tid >> 6, L = tid & 63;
    const int lane31 = L & 31, lhalf = L >> 5;
    const int lr = L & 15, lq = L >> 4;
    const int bx = blockIdx.x;
    const int b = bx >> 4, h = (bx >> 1) & 7, half_blk = bx & 1;
    const size_t base = (size_t)b * 512 * 384;

#pragma unroll
    for (int i = 0; i < 2; i++) {
        const int t = w + i * 8;
        const ushort_t* src = qkv + base + (size_t)(t * 32 + lane31) * 384 + 128 + h * 16 + lhalf * 8;
        gload16(src, &KF[t * 512 + L * 8]);
    }
    {
        const ushort_t* gv = qkv + base + (size_t)tid * 384 + 256 + h * 16;
        ushort_t tmp[16];
        *(uint4*)tmp = *(const uint4*)gv;
        *(uint4*)(tmp + 8) = *(const uint4*)(gv + 8);
#pragma unroll
        for (int d = 0; d < 16; d++) Vt[d * 520 + tid] = tmp[d];
    }
    __syncthreads();

    const int q0 = (half_blk * 8 + w) * 32;
    const short8 qf = *(const short8*)(qkv + base + (size_t)(q0 + lane31) * 384 + h * 16 + lhalf * 8);
    const uint_t* pmr = pm + (size_t)(b * 512 + q0 + lane31) * 16;
    const uint4 mwa = *(const uint4*)(pmr);
    const uint4 mwb = *(const uint4*)(pmr + 4);
    const uint4 mwc = *(const uint4*)(pmr + 8);
    const uint4 mwd = *(const uint4*)(pmr + 12);
    const uint_t mw[16] = {mwa.x, mwa.y, mwa.z, mwa.w, mwb.x, mwb.y, mwb.z, mwb.w,
                           mwc.x, mwc.y, mwc.z, mwc.w, mwd.x, mwd.y, mwd.z, mwd.w};

    const f32x16 zero16 = (f32x16)(0.f);

    float mx = -1e30f;
#pragma unroll
    for (int t = 0; t < 16; t++) {
        short8 kf = *(const short8*)&KF[t * 512 + L * 8];
        f32x16 s = __builtin_amdgcn_mfma_f32_32x32x16_bf16(kf, qf, zero16, 0, 0, 0);
#pragma unroll
        for (int r = 0; r < 16; r++) mx = fmaxf(mx, s[r]);
    }
    mx = fmaxf(mx, __shfl_xor(mx, 32));

    float lsum = 0.f;
    f32x4 oacc0 = (f32x4){0.f, 0.f, 0.f, 0.f};
    f32x4 oacc1 = (f32x4){0.f, 0.f, 0.f, 0.f};
#pragma unroll
    for (int t = 0; t < 16; t++) {
        short8 kf = *(const short8*)&KF[t * 512 + L * 8];
        f32x16 s = __builtin_amdgcn_mfma_f32_32x32x16_bf16(kf, qf, zero16, 0, 0, 0);
        const uint_t word = mw[t];
#pragma unroll
        for (int r = 0; r < 16; r++) {
            const int keyl = (r & 3) + 8 * (r >> 2) + 4 * lhalf;
            const float e = __expf(s[r] - mx);
            const float pv = (word & (1u << keyl)) ? e : 0.f;
            s[r] = pv;
            lsum += pv;
        }
#pragma unroll
        for (int g = 0; g < 4; g++) {
            const uint_t lo = pack2bf(s[g * 4 + 0], s[g * 4 + 1]);
            const uint_t hi = pack2bf(s[g * 4 + 2], s[g * 4 + 3]);
            *(uint2*)&Ps[w][lane31 * 36 + g * 8 + 4 * lhalf] = make_uint2(lo, hi);
        }
        short8 vb = *(const short8*)&Vt[lr * 520 + t * 32 + lq * 8];
        short8 pa0 = *(const short8*)&Ps[w][lr * 36 + lq * 8];
        short8 pa1 = *(const short8*)&Ps[w][(16 + lr) * 36 + lq * 8];
        oacc0 = __builtin_amdgcn_mfma_f32_16x16x32_bf16(pa0, vb, oacc0, 0, 0, 0);
        oacc1 = __builtin_amdgcn_mfma_f32_16x16x32_bf16(pa1, vb, oacc1, 0, 0, 0);
    }
    lsum += __shfl_xor(lsum, 32);

#pragma unroll
    for (int qa = 0; qa < 2; qa++) {
        const f32x4 oa = qa ? oacc1 : oacc0;
#pragma unroll
        for (int rr = 0; rr < 4; rr++) {
            const int qloc = qa * 16 + lq * 4 + rr;
            const float ls = __shfl(lsum, qloc, 64);
            const float ov = oa[rr] / ls;
            Aout[(size_t)(b * 512 + q0 + qloc) * 128 + h * 16 + lr] = f2bf(ov);
        }
    }
}

// ------------- pooled readout part (512 thr) -------------
__global__ __launch_bounds__(512) void pool_kernel(const float* __restrict__ h,
                                                   const float* __restrict__ Wp,
                                                   const float* __restrict__ Wr,
                                                   const float* __restrict__ br,
                                                   float* __restrict__ pb) {
    const int b = blockIdx.x, t = threadIdx.x;
    const int d = t & 127, g = t >> 7;
    __shared__ float part[4][128];
    __shared__ float pooled[128];
    __shared__ float rp[128];
    float acc = 0.f;
    const float* hb = h + (size_t)b * N_SEQ * D_EMB;
    for (int n = g; n < N_SEQ; n += 4) acc += hb[n * D_EMB + d];
    part[g][d] = acc;
    __syncthreads();
    if (t < 128) pooled[t] = (part[0][t] + part[1][t] + part[2][t] + part[3][t]) * (1.0f / N_SEQ);
    __syncthreads();
    float a2 = 0.f;
    for (int dd = g * 32; dd < g * 32 + 32; dd++) a2 += pooled[dd] * Wp[dd * 128 + d];
    part[g][d] = a2;
    __syncthreads();
    if (t < 128) rp[t] = fmaxf(part[0][t] + part[1][t] + part[2][t] + part[3][t], 0.f);
    __syncthreads();
    if (t < OUT_DIM) {
        float a = br[t];
        for (int j = 0; j < D_EMB; j++) a += rp[j] * Wr[j * OUT_DIM + t];
        pb[b * OUT_DIM + t] = a;
    }
}

// ------------- final readout -------------
__global__ __launch_bounds__(128) void out_kernel(const float* __restrict__ h,
                                                  const float* __restrict__ Wr,
                                                  const float* __restrict__ pb,
                                                  float* __restrict__ out) {
    const int row = blockIdx.x, tid = threadIdx.x;
    __shared__ float rp[128];
    rp[tid] = fmaxf(h[(size_t)row * D_EMB + tid], 0.f);
    __syncthreads();
    if (tid < 96) {
        const int o = tid >> 5, j0 = tid & 31;
        float acc = 0.f;
        for (int j = j0; j < 128; j += 32) acc += rp[j] * Wr[(128 + j) * OUT_DIM + o];
        for (int off = 16; off; off >>= 1) acc += __shfl_down(acc, off, 32);
        if (j0 == 0) out[(size_t)row * OUT_DIM + o] = acc + pb[(row >> 9) * OUT_DIM + o];
    }
}

extern "C" void kernel_launch(void* const* d_in, const int* in_sizes, int n_in,
                              void* d_out, int out_size, void* d_ws, size_t ws_size,
                              hipStream_t stream) {
    const float* x    = (const float*)d_in[0];
    const int*   mask = (const int*)d_in[1];
    const float* We   = (const float*)d_in[2];
    const float* Wq   = (const float*)d_in[3];
    const float* Wk   = (const float*)d_in[4];
    const float* Wv   = (const float*)d_in[5];
    const float* Wout = (const float*)d_in[6];
    const float* Wff1 = (const float*)d_in[7];
    const float* bff1 = (const float*)d_in[8];
    const float* Wff2 = (const float*)d_in[9];
    const float* bff2 = (const float*)d_in[10];
    const float* Wp   = (const float*)d_in[11];
    const float* Wr   = (const float*)d_in[12];
    const float* br   = (const float*)d_in[13];
    float* out = (float*)d_out;

    char* ws = (char*)d_ws;
    unsigned long long* pm64 = (unsigned long long*)(ws + 0);        // 1 MiB
    const uint_t* pm32       = (const uint_t*)(ws + 0);
    ushort_t* wqkvT = (ushort_t*)(ws + 1048576);                     // 288 KiB
    ushort_t* woutT = (ushort_t*)(ws + 1343488);                     // 96 KiB
    ushort_t* wff1T = (ushort_t*)(ws + 1441792);                     // 384 KiB
    ushort_t* wff2T = (ushort_t*)(ws + 1835008);                     // 384 KiB
    float*    pbbuf = (float*)(ws + 2228224);                        // 384 B
    float*    hbuf  = (float*)(ws + 4194304);                        // 8 MiB fp32 residual
    ushort_t* hb16  = (ushort_t*)(ws + 12582912);                    // 4 MiB bf16 mirror of h
    ushort_t* qkv16 = (ushort_t*)(ws + 16777216);                    // 12 MiB bf16 QKV
    ushort_t* a16   = (ushort_t*)(ws + 41943040);                    // 4 MiB bf16 attn out

    preproc_kernel<<<PM_BLK + RQ_BLK + TW_BLK + T1_BLK + T2_BLK + EM_BLK, 256, 0, stream>>>(
        mask, pm64, Wq, Wk, Wv, wqkvT, Wout, woutT, Wff1, wff1T, Wff2, wff2T,
        x, We, hbuf, hb16);

    for (int l = 0; l < L_LAYERS; l++) {
        // QKV (Q prescaled by 0.25 in epilogue of block x=0)
        gemm_qkv<<<dim3(3, M_ROWS / 128), 256, 0, stream>>>(
            hb16, wqkvT + (size_t)l * 384 * 128, qkv16, M_ROWS, 384, 128);
        // MFMA flash attention -> a16 bf16
        attn_mfma_kernel<<<512, 512, 0, stream>>>(qkv16, pm32, a16);
        // fused tail: h += a16@Wout ; h += relu(h@Wff1+b1)@Wff2+b2
        tail_kernel<<<M_ROWS / 32, 256, 0, stream>>>(
            a16, woutT + (size_t)l * 128 * 128, wff1T + (size_t)l * 512 * 128,
            wff2T + (size_t)l * 128 * 512, bff1 + l * 512, bff2 + l * 128,
            hbuf, hb16);
    }

    pool_kernel<<<B_BATCH, 512, 0, stream>>>(hbuf, Wp, Wr, br, pbbuf);
    out_kernel<<<M_ROWS, 128, 0, stream>>>(hbuf, Wr, pbbuf, out);
}